// Round 5
// baseline (132.716 us; speedup 1.0000x reference)
//
#include <hip/hip_runtime.h>
#include <math.h>

// AFM forward, round 5: bf16 embedding rows in LDS (halves LDS-pipe traffic,
// which r4 showed is the bottleneck). One wave = one sample, 32x32x16 MFMA
// per 32-pair tile (K=16 exact). Per tile each lane does exactly 2
// ds_read_b128 (its e-half of rows i and j) + 1 ds_read_b32 (pair table)
// + 1 swizzle; products unpacked to fp32 on the VALU (16 shifts/ands),
// packed back with single v_perm_b32 for the MFMA B-frag; pooling in fp32.
// proj_h pre-scaled by log2(e) -> bare v_exp_f32 per tile. Tail tile peeled.

#define BB 8192
#define FF 39
#define PP 741
#define NT 24                 // ceil(741/32); tiles 0..22 full, tile 23 has 5
#define RBYTES 48             // bf16 row stride: 32B data + 16B pad (16B-aligned)
#define SBYTES (FF * RBYTES)  // 1872 B per sample

typedef short bf16x8 __attribute__((ext_vector_type(8)));
typedef float f32x4  __attribute__((ext_vector_type(4)));
typedef float f32x16 __attribute__((ext_vector_type(16)));

// pack two fp32 -> dword of two bf16 (truncation), single v_perm_b32
static __device__ __forceinline__ unsigned pack2(float lo, float hi) {
    return __builtin_amdgcn_perm(__builtin_bit_cast(unsigned, hi),
                                 __builtin_bit_cast(unsigned, lo),
                                 0x07060302u);
}
static __device__ __forceinline__ float up_lo(unsigned d) {
    return __builtin_bit_cast(float, d << 16);
}
static __device__ __forceinline__ float up_hi(unsigned d) {
    return __builtin_bit_cast(float, d & 0xFFFF0000u);
}

__global__ __launch_bounds__(256)
void afm_kernel(const int*   __restrict__ fidx,
                const float* __restrict__ fval,
                const float* __restrict__ fow,
                const float* __restrict__ emb,
                const float* __restrict__ bias,
                const float* __restrict__ aw_,   // [E=16][A=16] row-major
                const float* __restrict__ ab_,   // [16]
                const float* __restrict__ ph_,   // [16]
                const float* __restrict__ pp_,   // [16]
                float*       __restrict__ out)
{
    __shared__ __align__(16) unsigned char s_emb[4 * SBYTES];  // 7488 B
    __shared__ unsigned s_pij[NT * 32];                        // 3072 B

    const int tid  = threadIdx.x;
    const int wid  = tid >> 6;
    const int lane = tid & 63;
    const int n    = lane & 31;      // pair slot within tile
    const int h    = lane >> 5;      // e-half / k-half
    const int smp  = blockIdx.x * 4 + wid;

    // ---- pair table (block-shared): (i*48)<<16 | (j*48) byte offsets ----
    if (tid < FF - 1) {
        int i = tid;
        int base = (i * (2 * FF - i - 1)) >> 1;
        for (int j = i + 1; j < FF; ++j)
            s_pij[base++] = ((unsigned)(i * RBYTES) << 16) | (unsigned)(j * RBYTES);
    } else if (tid == FF - 1) {
        for (int e = PP; e < NT * 32; ++e) s_pij[e] = 0u;  // dead slots
    }

    // ---- per-wave: indices, values, first-order term ----
    int ixr = 0; float vr = 0.f, fo = 0.f;
    if (lane < FF) {
        ixr = fidx[smp * FF + lane];
        vr  = fval[smp * FF + lane];
        fo  = fow[ixr] * vr;
    }
    #pragma unroll
    for (int m = 1; m < 64; m <<= 1) fo += __shfl_xor(fo, m);

    // ---- stage scaled rows as bf16 (78 half-row tasks of 16 B each) ----
    unsigned char* my = s_emb + wid * SBYTES;
    for (int u = lane; u < FF * 2; u += 64) {
        int row = u >> 1, hh = u & 1;
        int   ix = __shfl(ixr, row);
        float v  = __shfl(vr,  row);
        const float4* src = (const float4*)emb + (size_t)ix * 4 + hh * 2;
        float4 e0 = src[0], e1 = src[1];
        uint4 d = make_uint4(pack2(e0.x * v, e0.y * v),
                             pack2(e0.z * v, e0.w * v),
                             pack2(e1.x * v, e1.y * v),
                             pack2(e1.z * v, e1.w * v));
        *(uint4*)(my + row * RBYTES + hh * 16) = d;
    }

    // ---- constant fragments ----
    const float LOG2E = 1.44269504088896f;
    f32x4 h_lo = ((const f32x4*)ph_)[h];        // a = 4h + reg      (regs 0-3)
    f32x4 h_hi = ((const f32x4*)ph_)[h + 2];    // a = 8 + 4h + reg  (regs 4-7)
    #pragma unroll
    for (int r = 0; r < 4; ++r) { h_lo[r] *= LOG2E; h_hi[r] *= LOG2E; }

    f32x16 cinit;                               // bias rows a<16, zero above
    {
        const f32x4 ab_lo = ((const f32x4*)ab_)[h];
        const f32x4 ab_hi = ((const f32x4*)ab_)[h + 2];
        cinit[0] = ab_lo[0]; cinit[1] = ab_lo[1];
        cinit[2] = ab_lo[2]; cinit[3] = ab_lo[3];
        cinit[4] = ab_hi[0]; cinit[5] = ab_hi[1];
        cinit[6] = ab_hi[2]; cinit[7] = ab_hi[3];
        #pragma unroll
        for (int r = 8; r < 16; ++r) cinit[r] = 0.f;
    }

    bf16x8 wfrag;                               // A = W^T, rows m>=16 zero
    {
        float t0 = 0.f, t1 = 0.f, t2 = 0.f, t3 = 0.f,
              t4 = 0.f, t5 = 0.f, t6 = 0.f, t7 = 0.f;
        if (n < 16) {
            const float* base = aw_ + (8 * h) * 16 + n;  // W[k=8h+j][m=n]
            t0 = base[0];   t1 = base[16];  t2 = base[32];  t3 = base[48];
            t4 = base[64];  t5 = base[80];  t6 = base[96];  t7 = base[112];
        }
        union { unsigned i[4]; bf16x8 v; } u;
        u.i[0] = pack2(t0, t1); u.i[1] = pack2(t2, t3);
        u.i[2] = pack2(t4, t5); u.i[3] = pack2(t6, t7);
        wfrag = u.v;
    }

    __syncthreads();   // covers s_pij (+ staging, harmlessly)

    // ---- main loop: 23 full tiles + peeled masked tail ----
    const unsigned char* bpre = my + h * 16;    // this lane's e-half
    const unsigned* pijp = s_pij + n;
    float p0=0.f,p1=0.f,p2=0.f,p3=0.f,p4=0.f,p5=0.f,p6=0.f,p7=0.f;
    float z = 0.f;

#define TILE(PK, MASKED, MOK)                                             \
    {                                                                     \
        unsigned pk = (PK);                                               \
        uint4 di = *(const uint4*)(bpre + (pk >> 16));                    \
        uint4 dj = *(const uint4*)(bpre + (pk & 0xFFFFu));                \
        float m0 = up_lo(di.x) * up_lo(dj.x);                             \
        float m1 = up_hi(di.x) * up_hi(dj.x);                             \
        float m2 = up_lo(di.y) * up_lo(dj.y);                             \
        float m3 = up_hi(di.y) * up_hi(dj.y);                             \
        float m4 = up_lo(di.z) * up_lo(dj.z);                             \
        float m5 = up_hi(di.z) * up_hi(dj.z);                             \
        float m6 = up_lo(di.w) * up_lo(dj.w);                             \
        float m7 = up_hi(di.w) * up_hi(dj.w);                             \
        union { unsigned i[4]; bf16x8 v; } u;                             \
        u.i[0] = pack2(m0, m1); u.i[1] = pack2(m2, m3);                   \
        u.i[2] = pack2(m4, m5); u.i[3] = pack2(m6, m7);                   \
        f32x16 d = __builtin_amdgcn_mfma_f32_32x32x16_bf16(wfrag, u.v,    \
                                                           cinit, 0, 0, 0); \
        float s = fmaf(fmaxf(d[0], 0.f), h_lo[0],                         \
                  fmaf(fmaxf(d[1], 0.f), h_lo[1],                         \
                  fmaf(fmaxf(d[2], 0.f), h_lo[2],                         \
                  fmaf(fmaxf(d[3], 0.f), h_lo[3],                         \
                  fmaf(fmaxf(d[4], 0.f), h_hi[0],                         \
                  fmaf(fmaxf(d[5], 0.f), h_hi[1],                         \
                  fmaf(fmaxf(d[6], 0.f), h_hi[2],                         \
                       fmaxf(d[7], 0.f) * h_hi[3])))))));                 \
        s += __shfl_xor(s, 32);                                           \
        float w = __builtin_amdgcn_exp2f(s);                              \
        if (MASKED) w = (MOK) ? w : 0.f;                                  \
        z += w;                                                           \
        p0 = fmaf(w, m0, p0); p1 = fmaf(w, m1, p1);                       \
        p2 = fmaf(w, m2, p2); p3 = fmaf(w, m3, p3);                       \
        p4 = fmaf(w, m4, p4); p5 = fmaf(w, m5, p5);                       \
        p6 = fmaf(w, m6, p6); p7 = fmaf(w, m7, p7);                       \
    }

    #pragma unroll 4
    for (int t = 0; t < NT - 1; ++t)
        TILE(pijp[t * 32], false, true);
    TILE(pijp[(NT - 1) * 32], true, (n < PP - (NT - 1) * 32));
#undef TILE

    // ---- epilogue: aw = pooled . p ----
    const float4 pf0 = ((const float4*)pp_)[2 * h];
    const float4 pf1 = ((const float4*)pp_)[2 * h + 1];
    float awp = fmaf(p0, pf0.x, fmaf(p1, pf0.y, fmaf(p2, pf0.z,
                fmaf(p3, pf0.w, fmaf(p4, pf1.x, fmaf(p5, pf1.y,
                fmaf(p6, pf1.z, p7 * pf1.w)))))));
    #pragma unroll
    for (int m = 1; m < 64; m <<= 1) {
        awp += __shfl_xor(awp, m);
        z   += __shfl_xor(z, m);
    }
    if (lane == 0) {
        // lane-sum awp = aw (each e-half once); lane-sum z = 2*Z.
        float y = bias[0] + fo + 2.f * awp / z;
        out[smp] = 1.f / (1.f + __expf(-y));
    }
}

extern "C" void kernel_launch(void* const* d_in, const int* in_sizes, int n_in,
                              void* d_out, int out_size, void* d_ws, size_t ws_size,
                              hipStream_t stream) {
    const int*   fidx      = (const int*)  d_in[0];
    const float* fval      = (const float*)d_in[1];
    const float* fow       = (const float*)d_in[2];
    const float* emb_table = (const float*)d_in[3];
    const float* bias      = (const float*)d_in[4];
    const float* attn_w    = (const float*)d_in[5];
    const float* attn_b    = (const float*)d_in[6];
    const float* proj_h    = (const float*)d_in[7];
    const float* proj_p    = (const float*)d_in[8];
    float* out = (float*)d_out;

    afm_kernel<<<BB / 4, 256, 0, stream>>>(fidx, fval, fow, emb_table, bias,
                                           attn_w, attn_b, proj_h, proj_p, out);
}